// Round 7
// baseline (300.411 us; speedup 1.0000x reference)
//
#include <hip/hip_runtime.h>

#define CIN 8
#define FN 4
#define HSZ 256
#define NB 8

#define PV1F 16777216.0f                  /* 2^24 exactly */
#define PV2F 671088.0f                    /* floor(2^31/3200) */
#define ACT_C 1.7198652168210516e-07f     /* 2*log2(e)/2^24 */

// returns floor(tanh(floor(s)/2^24) * 2^24)  -- next layer's input, pre-scaled
__device__ __forceinline__ float act_t(float s) {
    float e = __builtin_amdgcn_exp2f(floorf(s) * ACT_C);
    float r = __builtin_amdgcn_rcpf(e + 1.0f);
    return floorf(fmaf(-33554432.0f, r, 16777216.0f));
}
// final layer: returns tanh(floor(s)/2^24)
__device__ __forceinline__ float act_out(float s) {
    float e = __builtin_amdgcn_exp2f(floorf(s) * ACT_C);
    float r = __builtin_amdgcn_rcpf(e + 1.0f);
    return fmaf(-2.0f, r, 1.0f);
}

// -------- prep: totalistic kernel (blocks 0..31) + weight transpose (32..35) --------
__global__ void k_prep(const float* __restrict__ kern,
                       const float* __restrict__ W2, const float* __restrict__ W3,
                       const float* __restrict__ W4,
                       float* __restrict__ ktot, float* __restrict__ w2t,
                       float* __restrict__ w3t, float* __restrict__ w4t) {
    int bb = blockIdx.x;
    int t = threadIdx.x;
    if (bb < 32) {
        const float* kk = kern + bb * 25;
        __shared__ float zsh[25];
        if (t < 25) {
            int i = t / 5, j = t % 5;
            float v = kk[i*5 + j] + kk[(4-i)*5 + j] + kk[i*5 + (4-j)] + kk[(4-i)*5 + (4-j)]
                    + kk[j*5 + i] + kk[j*5 + (4-i)] + kk[(4-j)*5 + i] + kk[(4-j)*5 + (4-i)];
            zsh[t] = 0.125f * v;
        }
        __syncthreads();
        if (t < 25) {
            float m = 0.0f;
            #pragma unroll
            for (int q = 0; q < 25; q++) m += zsh[q];
            m *= (1.0f / 25.0f);
            ktot[bb * 25 + t] = zsh[t] - m;
        }
    } else {
        int f = bb - 32;
        for (int e = t; e < 1024; e += 64) {
            int o = e >> 5, c = e & 31;
            w2t[f * 1024 + c * 32 + o] = W2[f * 1024 + e];
            w3t[f * 1024 + c * 32 + o] = W3[f * 1024 + e];
        }
        for (int e = t; e < 256; e += 64) {
            int o = e >> 5, c = e & 31;
            w4t[f * 256 + c * 8 + o] = W4[f * 256 + e];
        }
    }
}

// -------- main: one wave per filter, 64 pixels per block; activations in LDS --------
__global__ __launch_bounds__(256, 2) void k_main(
    const float* __restrict__ x, const float* __restrict__ ktot,
    const float* __restrict__ biases, const float* __restrict__ W1,
    const float* __restrict__ w2t, const float* __restrict__ w3t,
    const float* __restrict__ w4t, const unsigned* __restrict__ urate,
    float* __restrict__ out)
{
    int tid = threadIdx.x;
    int lane = tid & 63;
    int f = __builtin_amdgcn_readfirstlane(tid >> 6);   // wave-uniform -> SGPR

    int blk = blockIdx.x;            // 8192 = b(8) * h(256) * seg(4)
    int seg = blk & 3;
    int h   = (blk >> 2) & 255;
    int b   = blk >> 10;
    int w0  = seg << 6;

    // smem aliased: conv tile zt[8][5][68] (2720 floats), then act[32][256]
    __shared__ float smem[32 * 256];                 // 32 KB
    __shared__ float red[8][FN][64];                 // 8 KB
    float (*zt)[5][68] = reinterpret_cast<float(*)[5][68]>(smem);

    // ---- stage z = floor(x*PV2) for rows h-2..h+2, cols w0-2..w0+65 (wrapped) ----
    for (int e = tid; e < CIN * 5 * 68; e += 256) {
        int c  = e / (5 * 68);
        int r  = e % (5 * 68);
        int di = r / 68;
        int dj = r % 68;
        int hh = (h + di + 254) & 255;
        int ww = (w0 + dj + 254) & 255;
        float xv = x[((b * CIN + c) << 16) + (hh << 8) + ww];
        zt[c][di][dj] = floorf(xv * PV2F);
    }
    __syncthreads();

    // ---- conv for (pixel=lane, filter=f); 2 partial accs for ILP ----
    const float* kt = ktot + f * 200;     // [c][5][5], wave-uniform
    float accA = 0.f, accB = 0.f;
    #pragma unroll
    for (int c = 0; c < CIN; c++) {
        #pragma unroll
        for (int di = 0; di < 5; di++) {
            #pragma unroll
            for (int dj = 0; dj < 5; dj++) {
                float v = zt[c][di][lane + dj] * kt[c * 25 + di * 5 + dj];
                if ((di ^ c) & 1) accA += v; else accB += v;
            }
        }
    }
    float acc = accA + accB;
    __syncthreads();                      // all waves done reading zt; smem -> act

    // ---- MLP; activations live in act[c][tid] (per-thread column, no barriers) ----
    float p  = floorf(acc + biases[f]) / PV2F;
    float t0 = floorf(p * PV1F);

    const float* w1 = W1  + f * 32;
    const float* w2 = w2t + f * 1024;     // [c][o]
    const float* w3 = w3t + f * 1024;     // [c][o]
    const float* w4 = w4t + f * 256;      // [c][o]

    // layer 1 (c-dim == 1)
    #pragma unroll
    for (int o = 0; o < 32; o++)
        smem[o * 256 + tid] = act_t(w1[o] * t0);

    // layer 2
    {
        float s[32];
        #pragma unroll
        for (int o = 0; o < 32; o++) s[o] = 0.f;
        #pragma unroll
        for (int c = 0; c < 32; c++) {
            float tav = smem[c * 256 + tid];
            #pragma unroll
            for (int o = 0; o < 32; o++) s[o] = fmaf(w2[c * 32 + o], tav, s[o]);
        }
        #pragma unroll
        for (int o = 0; o < 32; o++) smem[o * 256 + tid] = act_t(s[o]);
    }

    // layer 3
    {
        float s[32];
        #pragma unroll
        for (int o = 0; o < 32; o++) s[o] = 0.f;
        #pragma unroll
        for (int c = 0; c < 32; c++) {
            float tav = smem[c * 256 + tid];
            #pragma unroll
            for (int o = 0; o < 32; o++) s[o] = fmaf(w3[c * 32 + o], tav, s[o]);
        }
        #pragma unroll
        for (int o = 0; o < 32; o++) smem[o * 256 + tid] = act_t(s[o]);
    }

    // layer 4 -> 8 outputs
    {
        float s[8];
        #pragma unroll
        for (int o = 0; o < 8; o++) s[o] = 0.f;
        #pragma unroll
        for (int c = 0; c < 32; c++) {
            float tav = smem[c * 256 + tid];
            #pragma unroll
            for (int o = 0; o < 8; o++) s[o] = fmaf(w4[c * 8 + o], tav, s[o]);
        }
        #pragma unroll
        for (int o = 0; o < 8; o++) red[o][f][lane] = act_out(s[o]);
    }
    __syncthreads();

    // ---- second-smallest across f + residual + clip; 2 (o,pixel) pairs/thread ----
    unsigned ub = urate[0];
    float ur = (ub < 0x38000000u) ? (float)(int)ub : __uint_as_float(ub);

    #pragma unroll
    for (int q = 0; q < 2; q++) {
        int pidx = tid + q * 256;
        int o   = pidx >> 6;
        int pix = pidx & 63;
        float v0 = red[o][0][pix], v1 = red[o][1][pix];
        float v2 = red[o][2][pix], v3 = red[o][3][pix];
        float lo01 = fminf(v0, v1), hi01 = fmaxf(v0, v1);
        float lo23 = fminf(v2, v3), hi23 = fmaxf(v2, v3);
        float second = fminf(fmaxf(lo01, lo23), fminf(hi01, hi23));
        int oidx = ((b * CIN + o) << 16) + (h << 8) + (w0 + pix);
        float xv = x[oidx];
        out[oidx] = fminf(fmaxf(xv + second * ur, 0.0f), 1.0f);
    }
}

extern "C" void kernel_launch(void* const* d_in, const int* in_sizes, int n_in,
                              void* d_out, int out_size, void* d_ws, size_t ws_size,
                              hipStream_t stream) {
    const float* x       = (const float*)d_in[0];
    const float* kernels = (const float*)d_in[1];
    const float* biases  = (const float*)d_in[2];
    const float* W1      = (const float*)d_in[3];
    const float* W2      = (const float*)d_in[4];
    const float* W3      = (const float*)d_in[5];
    const float* W4      = (const float*)d_in[6];
    const unsigned* ur   = (const unsigned*)d_in[7];
    float* out = (float*)d_out;

    float* ktot = (float*)d_ws;                 // 800 floats
    float* w2t  = ktot + 800;                   // 4096
    float* w3t  = w2t + 4096;                   // 4096
    float* w4t  = w3t + 4096;                   // 1024   (total 9.25K floats = 37 KB)

    k_prep<<<36, 64, 0, stream>>>(kernels, W2, W3, W4, ktot, w2t, w3t, w4t);
    k_main<<<NB * HSZ * 4, 256, 0, stream>>>(x, ktot, biases, W1, w2t, w3t, w4t, ur, out);
}